// Round 1
// baseline (320.353 us; speedup 1.0000x reference)
//
#include <hip/hip_runtime.h>
#include <math.h>

// GaussianKDE score_samples: out[i] = (1/N) * sum_j exp(x_i.y_j - 0.5||x_i||^2 - 0.5||y_j||^2 - 16*ln(2pi))
// N = M = 16384, D = 32, f32.
//
// Round 0: f32 VALU baseline. Compute-bound (no fp32 MFMA on CDNA4):
// floor = N*M*D FMA / 78.6 T-FMA/s ~= 109us. MFMA bf16-split comes next round.

#define D 32
#define BLOCK 256
#define JSPLIT 16
#define JPER 1024           // M / JSPLIT

// 16 * ln(2*pi)
#define C16LN2PI 29.406033062549527f

__global__ __launch_bounds__(BLOCK, 2) void kde_kernel(
    const float* __restrict__ X, const float* __restrict__ Y,
    float* __restrict__ out, int N, int M, float inv_n)
{
    const int tid = threadIdx.x;
    const int i   = blockIdx.x * BLOCK + tid;
    const int j0  = blockIdx.y * JPER;

    __shared__ float cy[JPER];

    // Stage cy_j = -0.5*||y_j||^2 - 16*ln(2pi) for this block's j-range.
    for (int jj = tid; jj < JPER; jj += BLOCK) {
        const float4* yv = (const float4*)(Y + (size_t)(j0 + jj) * D);
        float ny = 0.f;
#pragma unroll
        for (int q = 0; q < D / 4; ++q) {
            float4 y = yv[q];
            ny += y.x * y.x + y.y * y.y + y.z * y.z + y.w * y.w;
        }
        cy[jj] = -0.5f * ny - C16LN2PI;
    }
    __syncthreads();

    if (i >= N) return;

    // Load x_i into registers (32 floats = 8 float4).
    float4 xv[D / 4];
    const float4* xp = (const float4*)(X + (size_t)i * D);
    float nx = 0.f;
#pragma unroll
    for (int q = 0; q < D / 4; ++q) {
        xv[q] = xp[q];
        nx += xv[q].x * xv[q].x + xv[q].y * xv[q].y
            + xv[q].z * xv[q].z + xv[q].w * xv[q].w;
    }
    const float cx = -0.5f * nx;

    float acc = 0.f;
#pragma unroll 2
    for (int j = 0; j < JPER; ++j) {
        // Wave-uniform address -> expect scalar (s_load) Y reads.
        const float4* yv = (const float4*)(Y + (size_t)(j0 + j) * D);
        float d0 = 0.f, d1 = 0.f, d2 = 0.f, d3 = 0.f;   // 4-way ILP in the dot
#pragma unroll
        for (int q = 0; q < D / 4; ++q) {
            float4 y = yv[q];
            d0 = fmaf(xv[q].x, y.x, d0);
            d1 = fmaf(xv[q].y, y.y, d1);
            d2 = fmaf(xv[q].z, y.z, d2);
            d3 = fmaf(xv[q].w, y.w, d3);
        }
        const float dot = (d0 + d1) + (d2 + d3);
        acc += __expf(dot + cx + cy[j]);
    }

    atomicAdd(&out[i], acc * inv_n);
}

extern "C" void kernel_launch(void* const* d_in, const int* in_sizes, int n_in,
                              void* d_out, int out_size, void* d_ws, size_t ws_size,
                              hipStream_t stream) {
    (void)n_in; (void)d_ws; (void)ws_size;
    const float* X = (const float*)d_in[0];
    const float* Y = (const float*)d_in[1];
    float* out = (float*)d_out;
    const int N = in_sizes[0] / D;
    const int M = in_sizes[1] / D;

    hipMemsetAsync(d_out, 0, (size_t)out_size * sizeof(float), stream);

    dim3 grid((N + BLOCK - 1) / BLOCK, JSPLIT);
    kde_kernel<<<grid, BLOCK, 0, stream>>>(X, Y, out, N, M, 1.0f / (float)N);
}

// Round 2
// 81.860 us; speedup vs baseline: 3.9134x; 3.9134x over previous
//
#include <hip/hip_runtime.h>
#include <math.h>

// GaussianKDE: out[i] = (1/N) * sum_j exp(x_i.y_j - 0.5||x_i||^2 - 0.5||y_j||^2 - 16*ln(2pi))
// N = M = 16384, D = 32, f32 in/out.
//
// R2: bf16 MFMA path. dot' = log2e * x.y computed by 3x mfma_f32_16x16x32_bf16
// (hi/lo split of sqrt(log2e)-scaled inputs; K=32 == D, one MFMA per term).
// out_i = 2^cx'_i * sum_j 2^(dot'_ij + cy'_j), cx' hoisted out of the j-loop.

#define D 32
#define BLOCK 256
#define WAVES 4
#define WT 4                       // 16-row i-tiles per wave
#define ROWS_PER_WAVE (WT * 16)    // 64
#define ROWS_PER_BLOCK (WAVES * ROWS_PER_WAVE)  // 256
#define SPLITS 16

#define LOG2E 1.4426950408889634f
#define SQRT_LOG2E 1.2011224087864498f

typedef __attribute__((ext_vector_type(8))) short bf16x8;
typedef __attribute__((ext_vector_type(4))) float f32x4;

static __device__ __forceinline__ float fast_exp2(float x) {
    float r;
    asm volatile("v_exp_f32 %0, %1" : "=v"(r) : "v"(x));
    return r;
}

static __device__ __forceinline__ ushort bf16_rne(float f) {
    uint32_t u = __float_as_uint(f);
    u += 0x7FFFu + ((u >> 16) & 1u);
    return (ushort)(u >> 16);
}

// ---------------- precompute: f32 row -> scaled bf16 hi/lo + exponent const ----
__global__ void cvt_kernel(const float* __restrict__ src, ushort* __restrict__ hi,
                           ushort* __restrict__ lo, float* __restrict__ cvec,
                           int rows, float extra)
{
    int r = blockIdx.x * blockDim.x + threadIdx.x;
    if (r >= rows) return;
    const float4* p = (const float4*)(src + (size_t)r * D);
    float v[D];
    float nrm = 0.f;
#pragma unroll
    for (int q = 0; q < D / 4; ++q) {
        float4 f = p[q];
        v[q * 4 + 0] = f.x; v[q * 4 + 1] = f.y; v[q * 4 + 2] = f.z; v[q * 4 + 3] = f.w;
        nrm += f.x * f.x + f.y * f.y + f.z * f.z + f.w * f.w;
    }
    cvec[r] = -0.5f * LOG2E * nrm + extra;
    ushort hb[D], lb[D];
#pragma unroll
    for (int k = 0; k < D; ++k) {
        float s = v[k] * SQRT_LOG2E;
        ushort h = bf16_rne(s);
        float hf = __uint_as_float((uint32_t)h << 16);
        hb[k] = h;
        lb[k] = bf16_rne(s - hf);
    }
    ushort4* ho = (ushort4*)(hi + (size_t)r * D);
    ushort4* lro = (ushort4*)(lo + (size_t)r * D);
#pragma unroll
    for (int q = 0; q < D / 4; ++q) {
        ho[q]  = make_ushort4(hb[q*4+0], hb[q*4+1], hb[q*4+2], hb[q*4+3]);
        lro[q] = make_ushort4(lb[q*4+0], lb[q*4+1], lb[q*4+2], lb[q*4+3]);
    }
}

// ---------------- main MFMA kernel --------------------------------------------
__global__ __launch_bounds__(BLOCK, 4) void kde_mfma(
    const ushort* __restrict__ Xhi, const ushort* __restrict__ Xlo,
    const ushort* __restrict__ Yhi, const ushort* __restrict__ Ylo,
    const float* __restrict__ cx, const float* __restrict__ cy,
    float* __restrict__ out, int jchunk)
{
    const int lane = threadIdx.x & 63;
    const int wave = threadIdx.x >> 6;
    const int i0 = (blockIdx.x * WAVES + wave) * ROWS_PER_WAVE;
    const int j0 = blockIdx.y * jchunk;
    const int fr = lane & 15;        // A-row / B-col / C-col within tile
    const int ks = (lane >> 4) * 8;  // K slice base

    bf16x8 ahi[WT], alo[WT];
#pragma unroll
    for (int t = 0; t < WT; ++t) {
        size_t off = (size_t)(i0 + t * 16 + fr) * D + ks;
        ahi[t] = *(const bf16x8*)(Xhi + off);
        alo[t] = *(const bf16x8*)(Xlo + off);
    }

    float rs[WT][4];
#pragma unroll
    for (int t = 0; t < WT; ++t)
#pragma unroll
        for (int r = 0; r < 4; ++r) rs[t][r] = 0.f;

    const int ntile = jchunk >> 4;
    for (int jt = 0; jt < ntile; ++jt) {
        const int j = j0 + (jt << 4);
        const size_t boff = (size_t)(j + fr) * D + ks;
        const bf16x8 bhi = *(const bf16x8*)(Yhi + boff);
        const bf16x8 blo = *(const bf16x8*)(Ylo + boff);
        const float cyv = cy[j + fr];
#pragma unroll
        for (int t = 0; t < WT; ++t) {
            f32x4 acc = {0.f, 0.f, 0.f, 0.f};
            acc = __builtin_amdgcn_mfma_f32_16x16x32_bf16(ahi[t], bhi, acc, 0, 0, 0);
            acc = __builtin_amdgcn_mfma_f32_16x16x32_bf16(ahi[t], blo, acc, 0, 0, 0);
            acc = __builtin_amdgcn_mfma_f32_16x16x32_bf16(alo[t], bhi, acc, 0, 0, 0);
#pragma unroll
            for (int r = 0; r < 4; ++r)
                rs[t][r] += fast_exp2(acc[r] + cyv);
        }
    }

    // reduce across the 16 cols (lanes sharing lane>>4)
#pragma unroll
    for (int m = 1; m < 16; m <<= 1)
#pragma unroll
        for (int t = 0; t < WT; ++t)
#pragma unroll
            for (int r = 0; r < 4; ++r)
                rs[t][r] += __shfl_xor(rs[t][r], m, 64);

    if (fr == 0) {
        const int rowbase = i0 + (lane >> 4) * 4;
#pragma unroll
        for (int t = 0; t < WT; ++t)
#pragma unroll
            for (int r = 0; r < 4; ++r) {
                const int row = rowbase + t * 16 + r;
                atomicAdd(&out[row], rs[t][r] * fast_exp2(cx[row]));
            }
    }
}

// ---------------- fallback: verified R1 f32 VALU kernel -----------------------
#define FJSPLIT 16
#define FJPER 1024
#define C16LN2PI 29.406033062549527f

__global__ __launch_bounds__(BLOCK, 2) void kde_valu(
    const float* __restrict__ X, const float* __restrict__ Y,
    float* __restrict__ out, int N, int M, float inv_n)
{
    const int tid = threadIdx.x;
    const int i   = blockIdx.x * BLOCK + tid;
    const int j0  = blockIdx.y * FJPER;
    __shared__ float cys[FJPER];
    for (int jj = tid; jj < FJPER; jj += BLOCK) {
        const float4* yv = (const float4*)(Y + (size_t)(j0 + jj) * D);
        float ny = 0.f;
#pragma unroll
        for (int q = 0; q < D / 4; ++q) {
            float4 y = yv[q];
            ny += y.x * y.x + y.y * y.y + y.z * y.z + y.w * y.w;
        }
        cys[jj] = -0.5f * ny - C16LN2PI;
    }
    __syncthreads();
    if (i >= N) return;
    float4 xv[D / 4];
    const float4* xp = (const float4*)(X + (size_t)i * D);
    float nx = 0.f;
#pragma unroll
    for (int q = 0; q < D / 4; ++q) {
        xv[q] = xp[q];
        nx += xv[q].x * xv[q].x + xv[q].y * xv[q].y + xv[q].z * xv[q].z + xv[q].w * xv[q].w;
    }
    const float cxs = -0.5f * nx;
    float acc = 0.f;
#pragma unroll 2
    for (int j = 0; j < FJPER; ++j) {
        const float4* yv = (const float4*)(Y + (size_t)(j0 + j) * D);
        float d0 = 0.f, d1 = 0.f, d2 = 0.f, d3 = 0.f;
#pragma unroll
        for (int q = 0; q < D / 4; ++q) {
            float4 y = yv[q];
            d0 = fmaf(xv[q].x, y.x, d0);
            d1 = fmaf(xv[q].y, y.y, d1);
            d2 = fmaf(xv[q].z, y.z, d2);
            d3 = fmaf(xv[q].w, y.w, d3);
        }
        acc += __expf((d0 + d1) + (d2 + d3) + cxs + cys[j]);
    }
    atomicAdd(&out[i], acc * inv_n);
}

// ---------------- launch -------------------------------------------------------
extern "C" void kernel_launch(void* const* d_in, const int* in_sizes, int n_in,
                              void* d_out, int out_size, void* d_ws, size_t ws_size,
                              hipStream_t stream) {
    (void)n_in;
    const float* X = (const float*)d_in[0];
    const float* Y = (const float*)d_in[1];
    float* out = (float*)d_out;
    const int N = in_sizes[0] / D;
    const int M = in_sizes[1] / D;

    hipMemsetAsync(d_out, 0, (size_t)out_size * sizeof(float), stream);

    const size_t xhb = (size_t)N * D * sizeof(ushort);
    const size_t yhb = (size_t)M * D * sizeof(ushort);
    const size_t cxb = (size_t)N * sizeof(float);
    const size_t cyb = (size_t)M * sizeof(float);
    const size_t need = 2 * xhb + 2 * yhb + cxb + cyb;

    const bool ok = (ws_size >= need) && (N % ROWS_PER_BLOCK == 0) &&
                    (M % (16 * SPLITS) == 0);

    if (!ok) {
        dim3 grid((N + BLOCK - 1) / BLOCK, FJSPLIT);
        kde_valu<<<grid, BLOCK, 0, stream>>>(X, Y, out, N, M, 1.0f / (float)N);
        return;
    }

    char* w = (char*)d_ws;
    ushort* Xhi = (ushort*)w;              w += xhb;
    ushort* Xlo = (ushort*)w;              w += xhb;
    ushort* Yhi = (ushort*)w;              w += yhb;
    ushort* Ylo = (ushort*)w;              w += yhb;
    float*  cxv = (float*)w;               w += cxb;
    float*  cyv = (float*)w;

    const float extraY = (float)((double)LOG2E *
        (-16.0 * log(2.0 * M_PI) - log((double)N)));

    cvt_kernel<<<(N + BLOCK - 1) / BLOCK, BLOCK, 0, stream>>>(X, Xhi, Xlo, cxv, N, 0.f);
    cvt_kernel<<<(M + BLOCK - 1) / BLOCK, BLOCK, 0, stream>>>(Y, Yhi, Ylo, cyv, M, extraY);

    const int jchunk = M / SPLITS;
    dim3 grid(N / ROWS_PER_BLOCK, SPLITS);
    kde_mfma<<<grid, BLOCK, 0, stream>>>(Xhi, Xlo, Yhi, Ylo, cxv, cyv, out, jchunk);
}

// Round 4
// 76.051 us; speedup vs baseline: 4.2123x; 1.0764x over previous
//
#include <hip/hip_runtime.h>
#include <math.h>

// GaussianKDE: out[i] = (1/N) * sum_j exp(x_i.y_j - 0.5||x_i||^2 - 0.5||y_j||^2 - 16*ln(2pi))
// N = M = 16384, D = 32, f32 in/out.
//
// R4 = verified R2 base + exactly two changes:
//   1. SPLITS 16->32 (2048 blocks -> 8 blocks/CU; R2 was grid-limited at Occ 31%)
//   2. register prefetch of next B tile + cy (peeled loop, no select chain)
// Deliberately NOT: __launch_bounds__(,8) spill (prime suspect for R3's fail),
// C-operand cy fold, fused cvt. One step at a time.

#define D 32
#define BLOCK 256
#define WAVES 4
#define WT 4                       // 16-row i-tiles per wave
#define ROWS_PER_WAVE (WT * 16)    // 64
#define ROWS_PER_BLOCK (WAVES * ROWS_PER_WAVE)  // 256
#define SPLITS 32

#define LOG2E 1.4426950408889634f
#define SQRT_LOG2E 1.2011224087864498f

typedef __attribute__((ext_vector_type(8))) short bf16x8;
typedef __attribute__((ext_vector_type(4))) float f32x4;

static __device__ __forceinline__ float fast_exp2(float x) {
    float r;
    asm volatile("v_exp_f32 %0, %1" : "=v"(r) : "v"(x));
    return r;
}

static __device__ __forceinline__ ushort bf16_rne(float f) {
    uint32_t u = __float_as_uint(f);
    u += 0x7FFFu + ((u >> 16) & 1u);
    return (ushort)(u >> 16);
}

// ---------------- precompute: f32 row -> scaled bf16 hi/lo + exponent const ----
__global__ void cvt_kernel(const float* __restrict__ src, ushort* __restrict__ hi,
                           ushort* __restrict__ lo, float* __restrict__ cvec,
                           int rows, float extra)
{
    int r = blockIdx.x * blockDim.x + threadIdx.x;
    if (r >= rows) return;
    const float4* p = (const float4*)(src + (size_t)r * D);
    float v[D];
    float nrm = 0.f;
#pragma unroll
    for (int q = 0; q < D / 4; ++q) {
        float4 f = p[q];
        v[q * 4 + 0] = f.x; v[q * 4 + 1] = f.y; v[q * 4 + 2] = f.z; v[q * 4 + 3] = f.w;
        nrm += f.x * f.x + f.y * f.y + f.z * f.z + f.w * f.w;
    }
    cvec[r] = -0.5f * LOG2E * nrm + extra;
    ushort hb[D], lb[D];
#pragma unroll
    for (int k = 0; k < D; ++k) {
        float s = v[k] * SQRT_LOG2E;
        ushort h = bf16_rne(s);
        float hf = __uint_as_float((uint32_t)h << 16);
        hb[k] = h;
        lb[k] = bf16_rne(s - hf);
    }
    ushort4* ho = (ushort4*)(hi + (size_t)r * D);
    ushort4* lro = (ushort4*)(lo + (size_t)r * D);
#pragma unroll
    for (int q = 0; q < D / 4; ++q) {
        ho[q]  = make_ushort4(hb[q*4+0], hb[q*4+1], hb[q*4+2], hb[q*4+3]);
        lro[q] = make_ushort4(lb[q*4+0], lb[q*4+1], lb[q*4+2], lb[q*4+3]);
    }
}

// ---------------- main MFMA kernel --------------------------------------------
__global__ __launch_bounds__(BLOCK, 4) void kde_mfma(
    const ushort* __restrict__ Xhi, const ushort* __restrict__ Xlo,
    const ushort* __restrict__ Yhi, const ushort* __restrict__ Ylo,
    const float* __restrict__ cx, const float* __restrict__ cy,
    float* __restrict__ out, int jchunk)
{
    const int lane = threadIdx.x & 63;
    const int wave = threadIdx.x >> 6;
    const int i0 = (blockIdx.x * WAVES + wave) * ROWS_PER_WAVE;
    const int j0 = blockIdx.y * jchunk;
    const int fr = lane & 15;        // A-row / B-col / C-col within tile
    const int ks = (lane >> 4) * 8;  // K slice base

    bf16x8 ahi[WT], alo[WT];
#pragma unroll
    for (int t = 0; t < WT; ++t) {
        size_t off = (size_t)(i0 + t * 16 + fr) * D + ks;
        ahi[t] = *(const bf16x8*)(Xhi + off);
        alo[t] = *(const bf16x8*)(Xlo + off);
    }

    float rs[WT][4];
#pragma unroll
    for (int t = 0; t < WT; ++t)
#pragma unroll
        for (int r = 0; r < 4; ++r) rs[t][r] = 0.f;

    const int ntile = jchunk >> 4;
    size_t boff = (size_t)(j0 + fr) * D + ks;
    bf16x8 bhi = *(const bf16x8*)(Yhi + boff);
    bf16x8 blo = *(const bf16x8*)(Ylo + boff);
    float cyv = cy[j0 + fr];

    for (int jt = 0; jt < ntile - 1; ++jt) {
        const size_t nboff = boff + (size_t)(16 * D);   // next 16 j-rows
        const bf16x8 nbhi = *(const bf16x8*)(Yhi + nboff);
        const bf16x8 nblo = *(const bf16x8*)(Ylo + nboff);
        const float ncy = cy[j0 + ((jt + 1) << 4) + fr];

#pragma unroll
        for (int t = 0; t < WT; ++t) {
            f32x4 acc = {0.f, 0.f, 0.f, 0.f};
            acc = __builtin_amdgcn_mfma_f32_16x16x32_bf16(ahi[t], bhi, acc, 0, 0, 0);
            acc = __builtin_amdgcn_mfma_f32_16x16x32_bf16(ahi[t], blo, acc, 0, 0, 0);
            acc = __builtin_amdgcn_mfma_f32_16x16x32_bf16(alo[t], bhi, acc, 0, 0, 0);
#pragma unroll
            for (int r = 0; r < 4; ++r)
                rs[t][r] += fast_exp2(acc[r] + cyv);
        }
        bhi = nbhi; blo = nblo; cyv = ncy; boff = nboff;
    }

    // last j-tile (no prefetch)
#pragma unroll
    for (int t = 0; t < WT; ++t) {
        f32x4 acc = {0.f, 0.f, 0.f, 0.f};
        acc = __builtin_amdgcn_mfma_f32_16x16x32_bf16(ahi[t], bhi, acc, 0, 0, 0);
        acc = __builtin_amdgcn_mfma_f32_16x16x32_bf16(ahi[t], blo, acc, 0, 0, 0);
        acc = __builtin_amdgcn_mfma_f32_16x16x32_bf16(alo[t], bhi, acc, 0, 0, 0);
#pragma unroll
        for (int r = 0; r < 4; ++r)
            rs[t][r] += fast_exp2(acc[r] + cyv);
    }

    // reduce across the 16 cols (lanes sharing lane>>4)
#pragma unroll
    for (int m = 1; m < 16; m <<= 1)
#pragma unroll
        for (int t = 0; t < WT; ++t)
#pragma unroll
            for (int r = 0; r < 4; ++r)
                rs[t][r] += __shfl_xor(rs[t][r], m, 64);

    if (fr == 0) {
        const int rowbase = i0 + (lane >> 4) * 4;
#pragma unroll
        for (int t = 0; t < WT; ++t)
#pragma unroll
            for (int r = 0; r < 4; ++r) {
                const int row = rowbase + t * 16 + r;
                atomicAdd(&out[row], rs[t][r] * fast_exp2(cx[row]));
            }
    }
}

// ---------------- fallback: verified R1 f32 VALU kernel -----------------------
#define FJSPLIT 16
#define FJPER 1024
#define C16LN2PI 29.406033062549527f

__global__ __launch_bounds__(BLOCK, 2) void kde_valu(
    const float* __restrict__ X, const float* __restrict__ Y,
    float* __restrict__ out, int N, int M, float inv_n)
{
    const int tid = threadIdx.x;
    const int i   = blockIdx.x * BLOCK + tid;
    const int j0  = blockIdx.y * FJPER;
    __shared__ float cys[FJPER];
    for (int jj = tid; jj < FJPER; jj += BLOCK) {
        const float4* yv = (const float4*)(Y + (size_t)(j0 + jj) * D);
        float ny = 0.f;
#pragma unroll
        for (int q = 0; q < D / 4; ++q) {
            float4 y = yv[q];
            ny += y.x * y.x + y.y * y.y + y.z * y.z + y.w * y.w;
        }
        cys[jj] = -0.5f * ny - C16LN2PI;
    }
    __syncthreads();
    if (i >= N) return;
    float4 xv[D / 4];
    const float4* xp = (const float4*)(X + (size_t)i * D);
    float nx = 0.f;
#pragma unroll
    for (int q = 0; q < D / 4; ++q) {
        xv[q] = xp[q];
        nx += xv[q].x * xv[q].x + xv[q].y * xv[q].y + xv[q].z * xv[q].z + xv[q].w * xv[q].w;
    }
    const float cxs = -0.5f * nx;
    float acc = 0.f;
#pragma unroll 2
    for (int j = 0; j < FJPER; ++j) {
        const float4* yv = (const float4*)(Y + (size_t)(j0 + j) * D);
        float d0 = 0.f, d1 = 0.f, d2 = 0.f, d3 = 0.f;
#pragma unroll
        for (int q = 0; q < D / 4; ++q) {
            float4 y = yv[q];
            d0 = fmaf(xv[q].x, y.x, d0);
            d1 = fmaf(xv[q].y, y.y, d1);
            d2 = fmaf(xv[q].z, y.z, d2);
            d3 = fmaf(xv[q].w, y.w, d3);
        }
        acc += __expf((d0 + d1) + (d2 + d3) + cxs + cys[j]);
    }
    atomicAdd(&out[i], acc * inv_n);
}

// ---------------- launch -------------------------------------------------------
extern "C" void kernel_launch(void* const* d_in, const int* in_sizes, int n_in,
                              void* d_out, int out_size, void* d_ws, size_t ws_size,
                              hipStream_t stream) {
    (void)n_in;
    const float* X = (const float*)d_in[0];
    const float* Y = (const float*)d_in[1];
    float* out = (float*)d_out;
    const int N = in_sizes[0] / D;
    const int M = in_sizes[1] / D;

    hipMemsetAsync(d_out, 0, (size_t)out_size * sizeof(float), stream);

    const size_t xhb = (size_t)N * D * sizeof(ushort);
    const size_t yhb = (size_t)M * D * sizeof(ushort);
    const size_t cxb = (size_t)N * sizeof(float);
    const size_t cyb = (size_t)M * sizeof(float);
    const size_t need = 2 * xhb + 2 * yhb + cxb + cyb;

    const bool ok = (ws_size >= need) && (N % ROWS_PER_BLOCK == 0) &&
                    (M % (16 * SPLITS) == 0);

    if (!ok) {
        dim3 grid((N + BLOCK - 1) / BLOCK, FJSPLIT);
        kde_valu<<<grid, BLOCK, 0, stream>>>(X, Y, out, N, M, 1.0f / (float)N);
        return;
    }

    char* w = (char*)d_ws;
    ushort* Xhi = (ushort*)w;              w += xhb;
    ushort* Xlo = (ushort*)w;              w += xhb;
    ushort* Yhi = (ushort*)w;              w += yhb;
    ushort* Ylo = (ushort*)w;              w += yhb;
    float*  cxv = (float*)w;               w += cxb;
    float*  cyv = (float*)w;

    const float extraY = (float)((double)LOG2E *
        (-16.0 * log(2.0 * M_PI) - log((double)N)));

    cvt_kernel<<<(N + BLOCK - 1) / BLOCK, BLOCK, 0, stream>>>(X, Xhi, Xlo, cxv, N, 0.f);
    cvt_kernel<<<(M + BLOCK - 1) / BLOCK, BLOCK, 0, stream>>>(Y, Yhi, Ylo, cyv, M, extraY);

    const int jchunk = M / SPLITS;
    dim3 grid(N / ROWS_PER_BLOCK, SPLITS);
    kde_mfma<<<grid, BLOCK, 0, stream>>>(Xhi, Xlo, Yhi, Ylo, cxv, cyv, out, jchunk);
}

// Round 6
// 73.168 us; speedup vs baseline: 4.3783x; 1.0394x over previous
//
#include <hip/hip_runtime.h>
#include <math.h>

// GaussianKDE: out[i] = (1/N) * sum_j exp(x_i.y_j - 0.5||x_i||^2 - 0.5||y_j||^2 - 16*ln(2pi))
// N = M = 16384, D = 32, f32 in/out.
//
// R6 = R5 with ONE change: fast_exp2 inline asm -> __builtin_amdgcn_exp2f.
// Theory: R3/R5 failures were the inline-asm v_exp_f32 directly consuming the
// MFMA D-register (hazard/reorder across opaque asm, guide rule #18); R2/R4
// passed only because a compiler-generated v_add sat in between. The builtin
// keeps the raw v_exp_f32 but lets the compiler manage MFMA->VALU hazards.
// Retains R5's: cy folded into MFMA C operand; depth-2 B prefetch; SPLITS=32.

#define D 32
#define BLOCK 256
#define WAVES 4
#define WT 4                       // 16-row i-tiles per wave
#define ROWS_PER_WAVE (WT * 16)    // 64
#define ROWS_PER_BLOCK (WAVES * ROWS_PER_WAVE)  // 256
#define SPLITS 32

#define LOG2E 1.4426950408889634f
#define SQRT_LOG2E 1.2011224087864498f

typedef __attribute__((ext_vector_type(8))) short bf16x8;
typedef __attribute__((ext_vector_type(4))) float f32x4;

static __device__ __forceinline__ float fast_exp2(float x) {
    return __builtin_amdgcn_exp2f(x);   // v_exp_f32, compiler-visible
}

static __device__ __forceinline__ ushort bf16_rne(float f) {
    uint32_t u = __float_as_uint(f);
    u += 0x7FFFu + ((u >> 16) & 1u);
    return (ushort)(u >> 16);
}

// ---------------- precompute: f32 row -> scaled bf16 hi/lo + exponent const ----
__global__ void cvt_kernel(const float* __restrict__ src, ushort* __restrict__ hi,
                           ushort* __restrict__ lo, float* __restrict__ cvec,
                           int rows, float extra)
{
    int r = blockIdx.x * blockDim.x + threadIdx.x;
    if (r >= rows) return;
    const float4* p = (const float4*)(src + (size_t)r * D);
    float v[D];
    float nrm = 0.f;
#pragma unroll
    for (int q = 0; q < D / 4; ++q) {
        float4 f = p[q];
        v[q * 4 + 0] = f.x; v[q * 4 + 1] = f.y; v[q * 4 + 2] = f.z; v[q * 4 + 3] = f.w;
        nrm += f.x * f.x + f.y * f.y + f.z * f.z + f.w * f.w;
    }
    cvec[r] = -0.5f * LOG2E * nrm + extra;
    ushort hb[D], lb[D];
#pragma unroll
    for (int k = 0; k < D; ++k) {
        float s = v[k] * SQRT_LOG2E;
        ushort h = bf16_rne(s);
        float hf = __uint_as_float((uint32_t)h << 16);
        hb[k] = h;
        lb[k] = bf16_rne(s - hf);
    }
    ushort4* ho = (ushort4*)(hi + (size_t)r * D);
    ushort4* lro = (ushort4*)(lo + (size_t)r * D);
#pragma unroll
    for (int q = 0; q < D / 4; ++q) {
        ho[q]  = make_ushort4(hb[q*4+0], hb[q*4+1], hb[q*4+2], hb[q*4+3]);
        lro[q] = make_ushort4(lb[q*4+0], lb[q*4+1], lb[q*4+2], lb[q*4+3]);
    }
}

// ---------------- main MFMA kernel --------------------------------------------
__global__ __launch_bounds__(BLOCK, 4) void kde_mfma(
    const ushort* __restrict__ Xhi, const ushort* __restrict__ Xlo,
    const ushort* __restrict__ Yhi, const ushort* __restrict__ Ylo,
    const float* __restrict__ cx, const float* __restrict__ cy,
    float* __restrict__ out, int jchunk)
{
    const int lane = threadIdx.x & 63;
    const int wave = threadIdx.x >> 6;
    const int i0 = (blockIdx.x * WAVES + wave) * ROWS_PER_WAVE;
    const int j0 = blockIdx.y * jchunk;
    const int fr = lane & 15;        // A-row / B-col / C-col within tile
    const int ks = (lane >> 4) * 8;  // K slice base

    bf16x8 ahi[WT], alo[WT];
#pragma unroll
    for (int t = 0; t < WT; ++t) {
        size_t off = (size_t)(i0 + t * 16 + fr) * D + ks;
        ahi[t] = *(const bf16x8*)(Xhi + off);
        alo[t] = *(const bf16x8*)(Xlo + off);
    }

    float rs[WT][4];
#pragma unroll
    for (int t = 0; t < WT; ++t)
#pragma unroll
        for (int r = 0; r < 4; ++r) rs[t][r] = 0.f;

    // cy folded into MFMA C operand: acc starts at cyv (col = fr for all 4 regs)
#define KDE_COMPUTE(BH, BL, CYV)                                                  \
    do {                                                                          \
        _Pragma("unroll")                                                         \
        for (int t = 0; t < WT; ++t) {                                            \
            f32x4 acc = {(CYV), (CYV), (CYV), (CYV)};                             \
            acc = __builtin_amdgcn_mfma_f32_16x16x32_bf16(ahi[t], (BH), acc, 0, 0, 0); \
            acc = __builtin_amdgcn_mfma_f32_16x16x32_bf16(ahi[t], (BL), acc, 0, 0, 0); \
            acc = __builtin_amdgcn_mfma_f32_16x16x32_bf16(alo[t], (BH), acc, 0, 0, 0); \
            _Pragma("unroll")                                                     \
            for (int r = 0; r < 4; ++r)                                           \
                rs[t][r] += fast_exp2(acc[r]);                                    \
        }                                                                         \
    } while (0)

    const int ntile = jchunk >> 4;   // >= 3 guaranteed by launch guard
    size_t boff = (size_t)(j0 + fr) * D + ks;

    // depth-2 register pipeline
    bf16x8 bhi0 = *(const bf16x8*)(Yhi + boff);
    bf16x8 blo0 = *(const bf16x8*)(Ylo + boff);
    float  cy0  = cy[j0 + fr];
    bf16x8 bhi1 = *(const bf16x8*)(Yhi + boff + 16 * D);
    bf16x8 blo1 = *(const bf16x8*)(Ylo + boff + 16 * D);
    float  cy1  = cy[j0 + 16 + fr];

    for (int jt = 0; jt < ntile - 2; ++jt) {
        const size_t nboff = boff + (size_t)(32 * D);       // tile jt+2
        const bf16x8 nbhi = *(const bf16x8*)(Yhi + nboff);
        const bf16x8 nblo = *(const bf16x8*)(Ylo + nboff);
        const float  ncy  = cy[j0 + ((jt + 2) << 4) + fr];

        KDE_COMPUTE(bhi0, blo0, cy0);

        bhi0 = bhi1; blo0 = blo1; cy0 = cy1;
        bhi1 = nbhi; blo1 = nblo; cy1 = ncy;
        boff += (size_t)(16 * D);
    }
    KDE_COMPUTE(bhi0, blo0, cy0);
    KDE_COMPUTE(bhi1, blo1, cy1);
#undef KDE_COMPUTE

    // reduce across the 16 cols (lanes sharing lane>>4)
#pragma unroll
    for (int m = 1; m < 16; m <<= 1)
#pragma unroll
        for (int t = 0; t < WT; ++t)
#pragma unroll
            for (int r = 0; r < 4; ++r)
                rs[t][r] += __shfl_xor(rs[t][r], m, 64);

    if (fr == 0) {
        const int rowbase = i0 + (lane >> 4) * 4;
#pragma unroll
        for (int t = 0; t < WT; ++t)
#pragma unroll
            for (int r = 0; r < 4; ++r) {
                const int row = rowbase + t * 16 + r;
                atomicAdd(&out[row], rs[t][r] * fast_exp2(cx[row]));
            }
    }
}

// ---------------- fallback: verified R1 f32 VALU kernel -----------------------
#define FJSPLIT 16
#define FJPER 1024
#define C16LN2PI 29.406033062549527f

__global__ __launch_bounds__(BLOCK, 2) void kde_valu(
    const float* __restrict__ X, const float* __restrict__ Y,
    float* __restrict__ out, int N, int M, float inv_n)
{
    const int tid = threadIdx.x;
    const int i   = blockIdx.x * BLOCK + tid;
    const int j0  = blockIdx.y * FJPER;
    __shared__ float cys[FJPER];
    for (int jj = tid; jj < FJPER; jj += BLOCK) {
        const float4* yv = (const float4*)(Y + (size_t)(j0 + jj) * D);
        float ny = 0.f;
#pragma unroll
        for (int q = 0; q < D / 4; ++q) {
            float4 y = yv[q];
            ny += y.x * y.x + y.y * y.y + y.z * y.z + y.w * y.w;
        }
        cys[jj] = -0.5f * ny - C16LN2PI;
    }
    __syncthreads();
    if (i >= N) return;
    float4 xv[D / 4];
    const float4* xp = (const float4*)(X + (size_t)i * D);
    float nx = 0.f;
#pragma unroll
    for (int q = 0; q < D / 4; ++q) {
        xv[q] = xp[q];
        nx += xv[q].x * xv[q].x + xv[q].y * xv[q].y + xv[q].z * xv[q].z + xv[q].w * xv[q].w;
    }
    const float cxs = -0.5f * nx;
    float acc = 0.f;
#pragma unroll 2
    for (int j = 0; j < FJPER; ++j) {
        const float4* yv = (const float4*)(Y + (size_t)(j0 + j) * D);
        float d0 = 0.f, d1 = 0.f, d2 = 0.f, d3 = 0.f;
#pragma unroll
        for (int q = 0; q < D / 4; ++q) {
            float4 y = yv[q];
            d0 = fmaf(xv[q].x, y.x, d0);
            d1 = fmaf(xv[q].y, y.y, d1);
            d2 = fmaf(xv[q].z, y.z, d2);
            d3 = fmaf(xv[q].w, y.w, d3);
        }
        acc += __expf((d0 + d1) + (d2 + d3) + cxs + cys[j]);
    }
    atomicAdd(&out[i], acc * inv_n);
}

// ---------------- launch -------------------------------------------------------
extern "C" void kernel_launch(void* const* d_in, const int* in_sizes, int n_in,
                              void* d_out, int out_size, void* d_ws, size_t ws_size,
                              hipStream_t stream) {
    (void)n_in;
    const float* X = (const float*)d_in[0];
    const float* Y = (const float*)d_in[1];
    float* out = (float*)d_out;
    const int N = in_sizes[0] / D;
    const int M = in_sizes[1] / D;

    hipMemsetAsync(d_out, 0, (size_t)out_size * sizeof(float), stream);

    const size_t xhb = (size_t)N * D * sizeof(ushort);
    const size_t yhb = (size_t)M * D * sizeof(ushort);
    const size_t cxb = (size_t)N * sizeof(float);
    const size_t cyb = (size_t)M * sizeof(float);
    const size_t need = 2 * xhb + 2 * yhb + cxb + cyb;

    const bool ok = (ws_size >= need) && (N % ROWS_PER_BLOCK == 0) &&
                    (M % (16 * SPLITS) == 0) && ((M / SPLITS) >> 4) >= 3;

    if (!ok) {
        dim3 grid((N + BLOCK - 1) / BLOCK, FJSPLIT);
        kde_valu<<<grid, BLOCK, 0, stream>>>(X, Y, out, N, M, 1.0f / (float)N);
        return;
    }

    char* w = (char*)d_ws;
    ushort* Xhi = (ushort*)w;              w += xhb;
    ushort* Xlo = (ushort*)w;              w += xhb;
    ushort* Yhi = (ushort*)w;              w += yhb;
    ushort* Ylo = (ushort*)w;              w += yhb;
    float*  cxv = (float*)w;               w += cxb;
    float*  cyv = (float*)w;

    const float extraY = (float)((double)LOG2E *
        (-16.0 * log(2.0 * M_PI) - log((double)N)));

    cvt_kernel<<<(N + BLOCK - 1) / BLOCK, BLOCK, 0, stream>>>(X, Xhi, Xlo, cxv, N, 0.f);
    cvt_kernel<<<(M + BLOCK - 1) / BLOCK, BLOCK, 0, stream>>>(Y, Yhi, Ylo, cyv, M, extraY);

    const int jchunk = M / SPLITS;
    dim3 grid(N / ROWS_PER_BLOCK, SPLITS);
    kde_mfma<<<grid, BLOCK, 0, stream>>>(Xhi, Xlo, Yhi, Ylo, cxv, cyv, out, jchunk);
}

// Round 7
// 69.102 us; speedup vs baseline: 4.6359x; 1.0588x over previous
//
#include <hip/hip_runtime.h>
#include <math.h>

// GaussianKDE: out[i] = (1/N) * sum_j exp(x_i.y_j - 0.5||x_i||^2 - 0.5||y_j||^2 - 16*ln(2pi))
// N = M = 16384, D = 32, f32 in/out.
//
// R7 = verified R6 base + ONE structural change: 2-tile software pipeline.
// Per iter: MFMA tile0 -> acc0, MFMA tile1 -> acc1 (independent), then exps of
// both. exp(acc0) on the VALU overlaps acc1's MFMAs in the matrix pipe --
// breaks the per-wave MFMA-chain -> exp-chain serialization that left both
// pipes at ~30-50% (R6: MfmaUtil 32, VALUBusy 50, ~2.7 waves/SIMD resident).
// Keeps: cy folded into MFMA C operand, builtin exp2 (R6 fix), SPLITS=32.

#define D 32
#define BLOCK 256
#define WAVES 4
#define WT 4                       // 16-row i-tiles per wave
#define ROWS_PER_WAVE (WT * 16)    // 64
#define ROWS_PER_BLOCK (WAVES * ROWS_PER_WAVE)  // 256
#define SPLITS 32

#define LOG2E 1.4426950408889634f
#define SQRT_LOG2E 1.2011224087864498f

typedef __attribute__((ext_vector_type(8))) short bf16x8;
typedef __attribute__((ext_vector_type(4))) float f32x4;

static __device__ __forceinline__ float fast_exp2(float x) {
    return __builtin_amdgcn_exp2f(x);   // v_exp_f32, compiler-visible (R6 fix)
}

static __device__ __forceinline__ ushort bf16_rne(float f) {
    uint32_t u = __float_as_uint(f);
    u += 0x7FFFu + ((u >> 16) & 1u);
    return (ushort)(u >> 16);
}

// ---------------- precompute: f32 row -> scaled bf16 hi/lo + exponent const ----
__global__ void cvt_kernel(const float* __restrict__ src, ushort* __restrict__ hi,
                           ushort* __restrict__ lo, float* __restrict__ cvec,
                           int rows, float extra)
{
    int r = blockIdx.x * blockDim.x + threadIdx.x;
    if (r >= rows) return;
    const float4* p = (const float4*)(src + (size_t)r * D);
    float v[D];
    float nrm = 0.f;
#pragma unroll
    for (int q = 0; q < D / 4; ++q) {
        float4 f = p[q];
        v[q * 4 + 0] = f.x; v[q * 4 + 1] = f.y; v[q * 4 + 2] = f.z; v[q * 4 + 3] = f.w;
        nrm += f.x * f.x + f.y * f.y + f.z * f.z + f.w * f.w;
    }
    cvec[r] = -0.5f * LOG2E * nrm + extra;
    ushort hb[D], lb[D];
#pragma unroll
    for (int k = 0; k < D; ++k) {
        float s = v[k] * SQRT_LOG2E;
        ushort h = bf16_rne(s);
        float hf = __uint_as_float((uint32_t)h << 16);
        hb[k] = h;
        lb[k] = bf16_rne(s - hf);
    }
    ushort4* ho = (ushort4*)(hi + (size_t)r * D);
    ushort4* lro = (ushort4*)(lo + (size_t)r * D);
#pragma unroll
    for (int q = 0; q < D / 4; ++q) {
        ho[q]  = make_ushort4(hb[q*4+0], hb[q*4+1], hb[q*4+2], hb[q*4+3]);
        lro[q] = make_ushort4(lb[q*4+0], lb[q*4+1], lb[q*4+2], lb[q*4+3]);
    }
}

// ---------------- main MFMA kernel --------------------------------------------
__global__ __launch_bounds__(BLOCK, 4) void kde_mfma(
    const ushort* __restrict__ Xhi, const ushort* __restrict__ Xlo,
    const ushort* __restrict__ Yhi, const ushort* __restrict__ Ylo,
    const float* __restrict__ cx, const float* __restrict__ cy,
    float* __restrict__ out, int jchunk)
{
    const int lane = threadIdx.x & 63;
    const int wave = threadIdx.x >> 6;
    const int i0 = (blockIdx.x * WAVES + wave) * ROWS_PER_WAVE;
    const int j0 = blockIdx.y * jchunk;
    const int fr = lane & 15;        // A-row / B-col / C-col within tile
    const int ks = (lane >> 4) * 8;  // K slice base

    bf16x8 ahi[WT], alo[WT];
#pragma unroll
    for (int t = 0; t < WT; ++t) {
        size_t off = (size_t)(i0 + t * 16 + fr) * D + ks;
        ahi[t] = *(const bf16x8*)(Xhi + off);
        alo[t] = *(const bf16x8*)(Xlo + off);
    }

    float rs[WT][4];
#pragma unroll
    for (int t = 0; t < WT; ++t)
#pragma unroll
        for (int r = 0; r < 4; ++r) rs[t][r] = 0.f;

    // cy folded into MFMA C operand (col = fr for all 4 C-regs)
#define KDE_MFMA_SET(ACC, BH, BL, CYV)                                          \
    _Pragma("unroll")                                                           \
    for (int t = 0; t < WT; ++t) {                                              \
        ACC[t] = (f32x4){(CYV), (CYV), (CYV), (CYV)};                           \
        ACC[t] = __builtin_amdgcn_mfma_f32_16x16x32_bf16(ahi[t], (BH), ACC[t], 0, 0, 0); \
        ACC[t] = __builtin_amdgcn_mfma_f32_16x16x32_bf16(ahi[t], (BL), ACC[t], 0, 0, 0); \
        ACC[t] = __builtin_amdgcn_mfma_f32_16x16x32_bf16(alo[t], (BH), ACC[t], 0, 0, 0); \
    }

#define KDE_EXP_SET(ACC)                                                        \
    _Pragma("unroll")                                                           \
    for (int t = 0; t < WT; ++t)                                                \
        _Pragma("unroll")                                                       \
        for (int r = 0; r < 4; ++r)                                             \
            rs[t][r] += fast_exp2(ACC[t][r]);

    const int ntile = jchunk >> 4;   // even, >= 4 guaranteed by launch guard
    const ushort* bhp = Yhi + (size_t)(j0 + fr) * D + ks;
    const ushort* blp = Ylo + (size_t)(j0 + fr) * D + ks;
    const float*  cyp = cy + j0 + fr;

    bf16x8 bhi0 = *(const bf16x8*)(bhp);
    bf16x8 blo0 = *(const bf16x8*)(blp);
    float  cy0  = cyp[0];
    bf16x8 bhi1 = *(const bf16x8*)(bhp + 16 * D);
    bf16x8 blo1 = *(const bf16x8*)(blp + 16 * D);
    float  cy1  = cyp[16];

    f32x4 acc0[WT], acc1[WT];

    for (int jt = 0; jt < ntile - 2; jt += 2) {
        const size_t o2 = (size_t)(jt + 2) * 16 * D;        // tile jt+2
        const size_t o3 = (size_t)(jt + 3) * 16 * D;        // tile jt+3
        const bf16x8 nh0 = *(const bf16x8*)(bhp + o2);
        const bf16x8 nl0 = *(const bf16x8*)(blp + o2);
        const bf16x8 nh1 = *(const bf16x8*)(bhp + o3);
        const bf16x8 nl1 = *(const bf16x8*)(blp + o3);
        const float ncy0 = cyp[(jt + 2) << 4];
        const float ncy1 = cyp[(jt + 3) << 4];

        KDE_MFMA_SET(acc0, bhi0, blo0, cy0);
        KDE_MFMA_SET(acc1, bhi1, blo1, cy1);
        KDE_EXP_SET(acc0);                    // VALU overlaps acc1's MFMAs
        KDE_EXP_SET(acc1);

        bhi0 = nh0; blo0 = nl0; cy0 = ncy0;
        bhi1 = nh1; blo1 = nl1; cy1 = ncy1;
    }
    // last pair (no prefetch)
    KDE_MFMA_SET(acc0, bhi0, blo0, cy0);
    KDE_MFMA_SET(acc1, bhi1, blo1, cy1);
    KDE_EXP_SET(acc0);
    KDE_EXP_SET(acc1);
#undef KDE_MFMA_SET
#undef KDE_EXP_SET

    // reduce across the 16 cols (lanes sharing lane>>4)
#pragma unroll
    for (int m = 1; m < 16; m <<= 1)
#pragma unroll
        for (int t = 0; t < WT; ++t)
#pragma unroll
            for (int r = 0; r < 4; ++r)
                rs[t][r] += __shfl_xor(rs[t][r], m, 64);

    if (fr == 0) {
        const int rowbase = i0 + (lane >> 4) * 4;
#pragma unroll
        for (int t = 0; t < WT; ++t)
#pragma unroll
            for (int r = 0; r < 4; ++r) {
                const int row = rowbase + t * 16 + r;
                atomicAdd(&out[row], rs[t][r] * fast_exp2(cx[row]));
            }
    }
}

// ---------------- fallback: verified R1 f32 VALU kernel -----------------------
#define FJSPLIT 16
#define FJPER 1024
#define C16LN2PI 29.406033062549527f

__global__ __launch_bounds__(BLOCK, 2) void kde_valu(
    const float* __restrict__ X, const float* __restrict__ Y,
    float* __restrict__ out, int N, int M, float inv_n)
{
    const int tid = threadIdx.x;
    const int i   = blockIdx.x * BLOCK + tid;
    const int j0  = blockIdx.y * FJPER;
    __shared__ float cys[FJPER];
    for (int jj = tid; jj < FJPER; jj += BLOCK) {
        const float4* yv = (const float4*)(Y + (size_t)(j0 + jj) * D);
        float ny = 0.f;
#pragma unroll
        for (int q = 0; q < D / 4; ++q) {
            float4 y = yv[q];
            ny += y.x * y.x + y.y * y.y + y.z * y.z + y.w * y.w;
        }
        cys[jj] = -0.5f * ny - C16LN2PI;
    }
    __syncthreads();
    if (i >= N) return;
    float4 xv[D / 4];
    const float4* xp = (const float4*)(X + (size_t)i * D);
    float nx = 0.f;
#pragma unroll
    for (int q = 0; q < D / 4; ++q) {
        xv[q] = xp[q];
        nx += xv[q].x * xv[q].x + xv[q].y * xv[q].y + xv[q].z * xv[q].z + xv[q].w * xv[q].w;
    }
    const float cxs = -0.5f * nx;
    float acc = 0.f;
#pragma unroll 2
    for (int j = 0; j < FJPER; ++j) {
        const float4* yv = (const float4*)(Y + (size_t)(j0 + j) * D);
        float d0 = 0.f, d1 = 0.f, d2 = 0.f, d3 = 0.f;
#pragma unroll
        for (int q = 0; q < D / 4; ++q) {
            float4 y = yv[q];
            d0 = fmaf(xv[q].x, y.x, d0);
            d1 = fmaf(xv[q].y, y.y, d1);
            d2 = fmaf(xv[q].z, y.z, d2);
            d3 = fmaf(xv[q].w, y.w, d3);
        }
        acc += __expf((d0 + d1) + (d2 + d3) + cxs + cys[j]);
    }
    atomicAdd(&out[i], acc * inv_n);
}

// ---------------- launch -------------------------------------------------------
extern "C" void kernel_launch(void* const* d_in, const int* in_sizes, int n_in,
                              void* d_out, int out_size, void* d_ws, size_t ws_size,
                              hipStream_t stream) {
    (void)n_in;
    const float* X = (const float*)d_in[0];
    const float* Y = (const float*)d_in[1];
    float* out = (float*)d_out;
    const int N = in_sizes[0] / D;
    const int M = in_sizes[1] / D;

    hipMemsetAsync(d_out, 0, (size_t)out_size * sizeof(float), stream);

    const size_t xhb = (size_t)N * D * sizeof(ushort);
    const size_t yhb = (size_t)M * D * sizeof(ushort);
    const size_t cxb = (size_t)N * sizeof(float);
    const size_t cyb = (size_t)M * sizeof(float);
    const size_t need = 2 * xhb + 2 * yhb + cxb + cyb;

    const int jchunk = M / SPLITS;
    const int ntile = jchunk >> 4;
    const bool ok = (ws_size >= need) && (N % ROWS_PER_BLOCK == 0) &&
                    (M % (16 * SPLITS) == 0) && (ntile >= 4) && ((ntile & 1) == 0);

    if (!ok) {
        dim3 grid((N + BLOCK - 1) / BLOCK, FJSPLIT);
        kde_valu<<<grid, BLOCK, 0, stream>>>(X, Y, out, N, M, 1.0f / (float)N);
        return;
    }

    char* w = (char*)d_ws;
    ushort* Xhi = (ushort*)w;              w += xhb;
    ushort* Xlo = (ushort*)w;              w += xhb;
    ushort* Yhi = (ushort*)w;              w += yhb;
    ushort* Ylo = (ushort*)w;              w += yhb;
    float*  cxv = (float*)w;               w += cxb;
    float*  cyv = (float*)w;

    const float extraY = (float)((double)LOG2E *
        (-16.0 * log(2.0 * M_PI) - log((double)N)));

    cvt_kernel<<<(N + BLOCK - 1) / BLOCK, BLOCK, 0, stream>>>(X, Xhi, Xlo, cxv, N, 0.f);
    cvt_kernel<<<(M + BLOCK - 1) / BLOCK, BLOCK, 0, stream>>>(Y, Yhi, Ylo, cyv, M, extraY);

    dim3 grid(N / ROWS_PER_BLOCK, SPLITS);
    kde_mfma<<<grid, BLOCK, 0, stream>>>(Xhi, Xlo, Yhi, Ylo, cxv, cyv, out, jchunk);
}

// Round 8
// 68.828 us; speedup vs baseline: 4.6544x; 1.0040x over previous
//
#include <hip/hip_runtime.h>
#include <math.h>

// GaussianKDE: out[i] = (1/N) * sum_j exp(x_i.y_j - 0.5||x_i||^2 - 0.5||y_j||^2 - 16*ln(2pi))
// N = M = 16384, D = 32, f32 in/out.
//
// R8 = R7 base, ONE structural change: fine-grained MFMA||exp interleave.
// Per t: {3-MFMA chain of tile jt+1} immediately followed by {4 exps of tile
// jt}. Both pipes get work from every wave at ~50-cyc granularity instead of
// R7's 24-MFMA-then-32-exp bursts (busy times were invariant: VALU 31us,
// MFMA 21us, combined issue ~87% -- burst-phase contention). Same math,
// same accumulation order -> bit-identical result.

#define D 32
#define BLOCK 256
#define WAVES 4
#define WT 4                       // 16-row i-tiles per wave
#define ROWS_PER_WAVE (WT * 16)    // 64
#define ROWS_PER_BLOCK (WAVES * ROWS_PER_WAVE)  // 256
#define SPLITS 32

#define LOG2E 1.4426950408889634f
#define SQRT_LOG2E 1.2011224087864498f

typedef __attribute__((ext_vector_type(8))) short bf16x8;
typedef __attribute__((ext_vector_type(4))) float f32x4;

static __device__ __forceinline__ float fast_exp2(float x) {
    return __builtin_amdgcn_exp2f(x);   // v_exp_f32, compiler-visible (R6 fix)
}

static __device__ __forceinline__ ushort bf16_rne(float f) {
    uint32_t u = __float_as_uint(f);
    u += 0x7FFFu + ((u >> 16) & 1u);
    return (ushort)(u >> 16);
}

#define MFMA16(A, B, C) __builtin_amdgcn_mfma_f32_16x16x32_bf16((A), (B), (C), 0, 0, 0)

// ---------------- precompute: f32 row -> scaled bf16 hi/lo + exponent const ----
__global__ void cvt_kernel(const float* __restrict__ src, ushort* __restrict__ hi,
                           ushort* __restrict__ lo, float* __restrict__ cvec,
                           int rows, float extra)
{
    int r = blockIdx.x * blockDim.x + threadIdx.x;
    if (r >= rows) return;
    const float4* p = (const float4*)(src + (size_t)r * D);
    float v[D];
    float nrm = 0.f;
#pragma unroll
    for (int q = 0; q < D / 4; ++q) {
        float4 f = p[q];
        v[q * 4 + 0] = f.x; v[q * 4 + 1] = f.y; v[q * 4 + 2] = f.z; v[q * 4 + 3] = f.w;
        nrm += f.x * f.x + f.y * f.y + f.z * f.z + f.w * f.w;
    }
    cvec[r] = -0.5f * LOG2E * nrm + extra;
    ushort hb[D], lb[D];
#pragma unroll
    for (int k = 0; k < D; ++k) {
        float s = v[k] * SQRT_LOG2E;
        ushort h = bf16_rne(s);
        float hf = __uint_as_float((uint32_t)h << 16);
        hb[k] = h;
        lb[k] = bf16_rne(s - hf);
    }
    ushort4* ho = (ushort4*)(hi + (size_t)r * D);
    ushort4* lro = (ushort4*)(lo + (size_t)r * D);
#pragma unroll
    for (int q = 0; q < D / 4; ++q) {
        ho[q]  = make_ushort4(hb[q*4+0], hb[q*4+1], hb[q*4+2], hb[q*4+3]);
        lro[q] = make_ushort4(lb[q*4+0], lb[q*4+1], lb[q*4+2], lb[q*4+3]);
    }
}

// ---------------- main MFMA kernel --------------------------------------------
__global__ __launch_bounds__(BLOCK, 4) void kde_mfma(
    const ushort* __restrict__ Xhi, const ushort* __restrict__ Xlo,
    const ushort* __restrict__ Yhi, const ushort* __restrict__ Ylo,
    const float* __restrict__ cx, const float* __restrict__ cy,
    float* __restrict__ out, int jchunk)
{
    const int lane = threadIdx.x & 63;
    const int wave = threadIdx.x >> 6;
    const int i0 = (blockIdx.x * WAVES + wave) * ROWS_PER_WAVE;
    const int j0 = blockIdx.y * jchunk;
    const int fr = lane & 15;        // A-row / B-col / C-col within tile
    const int ks = (lane >> 4) * 8;  // K slice base

    bf16x8 ahi[WT], alo[WT];
#pragma unroll
    for (int t = 0; t < WT; ++t) {
        size_t off = (size_t)(i0 + t * 16 + fr) * D + ks;
        ahi[t] = *(const bf16x8*)(Xhi + off);
        alo[t] = *(const bf16x8*)(Xlo + off);
    }

    float rs[WT][4];
#pragma unroll
    for (int t = 0; t < WT; ++t)
#pragma unroll
        for (int r = 0; r < 4; ++r) rs[t][r] = 0.f;

    const int ntile = jchunk >> 4;   // even, >= 4 guaranteed by launch guard
    const ushort* bhp = Yhi + (size_t)(j0 + fr) * D + ks;
    const ushort* blp = Ylo + (size_t)(j0 + fr) * D + ks;
    const float*  cyp = cy + j0 + fr;

#define TILEOFF(T) ((size_t)(T) * (16 * D))

    // B slots: tile jt lives in slot (jt & 1)
    bf16x8 bh0 = *(const bf16x8*)(bhp + TILEOFF(0));
    bf16x8 bl0 = *(const bf16x8*)(blp + TILEOFF(0));
    float  cv0 = cyp[0];
    bf16x8 bh1 = *(const bf16x8*)(bhp + TILEOFF(1));
    bf16x8 bl1 = *(const bf16x8*)(blp + TILEOFF(1));
    float  cv1 = cyp[16];

    f32x4 accA[WT], accB[WT];

    // warm-up: tile 0 (slot0) -> accA, no exps yet
    {
        const f32x4 cc = {cv0, cv0, cv0, cv0};
#pragma unroll
        for (int t = 0; t < WT; ++t) {
            f32x4 a = MFMA16(ahi[t], bh0, cc);
            a = MFMA16(ahi[t], bl0, a);
            accA[t] = MFMA16(alo[t], bh0, a);
        }
    }
    // prefetch tile 2 -> slot0 (slot0's tile-0 data is consumed)
    bh0 = *(const bf16x8*)(bhp + TILEOFF(2));
    bl0 = *(const bf16x8*)(blp + TILEOFF(2));
    cv0 = cyp[2 * 16];

    const int npair = (ntile - 2) >> 1;   // pairs cover tiles 1 .. ntile-2
    for (int p = 0; p < npair; ++p) {
        const int jt = 1 + 2 * p;

        // step 1: compute tile jt (slot1) -> accB; exp(accA); prefetch jt+2 -> slot1
        {
            const int pf = (jt + 2 <= ntile - 1) ? (jt + 2) : (ntile - 1);
            const bf16x8 nh = *(const bf16x8*)(bhp + TILEOFF(pf));
            const bf16x8 nl = *(const bf16x8*)(blp + TILEOFF(pf));
            const float ncv = cyp[pf * 16];
            const f32x4 cc = {cv1, cv1, cv1, cv1};
#pragma unroll
            for (int t = 0; t < WT; ++t) {
                f32x4 a = MFMA16(ahi[t], bh1, cc);
                a = MFMA16(ahi[t], bl1, a);
                accB[t] = MFMA16(alo[t], bh1, a);
#pragma unroll
                for (int r = 0; r < 4; ++r)
                    rs[t][r] += fast_exp2(accA[t][r]);   // VALU overlaps MFMAs
            }
            bh1 = nh; bl1 = nl; cv1 = ncv;
        }

        // step 2: compute tile jt+1 (slot0) -> accA; exp(accB); prefetch jt+3 -> slot0
        {
            const int pf = (jt + 3 <= ntile - 1) ? (jt + 3) : (ntile - 1);
            const bf16x8 nh = *(const bf16x8*)(bhp + TILEOFF(pf));
            const bf16x8 nl = *(const bf16x8*)(blp + TILEOFF(pf));
            const float ncv = cyp[pf * 16];
            const f32x4 cc = {cv0, cv0, cv0, cv0};
#pragma unroll
            for (int t = 0; t < WT; ++t) {
                f32x4 a = MFMA16(ahi[t], bh0, cc);
                a = MFMA16(ahi[t], bl0, a);
                accA[t] = MFMA16(alo[t], bh0, a);
#pragma unroll
                for (int r = 0; r < 4; ++r)
                    rs[t][r] += fast_exp2(accB[t][r]);
            }
            bh0 = nh; bl0 = nl; cv0 = ncv;
        }
    }

    // tail: tile ntile-1 (odd -> slot1): compute -> accB; exp(accA); then exp(accB)
    {
        const f32x4 cc = {cv1, cv1, cv1, cv1};
#pragma unroll
        for (int t = 0; t < WT; ++t) {
            f32x4 a = MFMA16(ahi[t], bh1, cc);
            a = MFMA16(ahi[t], bl1, a);
            accB[t] = MFMA16(alo[t], bh1, a);
#pragma unroll
            for (int r = 0; r < 4; ++r)
                rs[t][r] += fast_exp2(accA[t][r]);
        }
#pragma unroll
        for (int t = 0; t < WT; ++t)
#pragma unroll
            for (int r = 0; r < 4; ++r)
                rs[t][r] += fast_exp2(accB[t][r]);
    }
#undef TILEOFF

    // reduce across the 16 cols (lanes sharing lane>>4)
#pragma unroll
    for (int m = 1; m < 16; m <<= 1)
#pragma unroll
        for (int t = 0; t < WT; ++t)
#pragma unroll
            for (int r = 0; r < 4; ++r)
                rs[t][r] += __shfl_xor(rs[t][r], m, 64);

    if (fr == 0) {
        const int rowbase = i0 + (lane >> 4) * 4;
#pragma unroll
        for (int t = 0; t < WT; ++t)
#pragma unroll
            for (int r = 0; r < 4; ++r) {
                const int row = rowbase + t * 16 + r;
                atomicAdd(&out[row], rs[t][r] * fast_exp2(cx[row]));
            }
    }
}

// ---------------- fallback: verified R1 f32 VALU kernel -----------------------
#define FJSPLIT 16
#define FJPER 1024
#define C16LN2PI 29.406033062549527f

__global__ __launch_bounds__(BLOCK, 2) void kde_valu(
    const float* __restrict__ X, const float* __restrict__ Y,
    float* __restrict__ out, int N, int M, float inv_n)
{
    const int tid = threadIdx.x;
    const int i   = blockIdx.x * BLOCK + tid;
    const int j0  = blockIdx.y * FJPER;
    __shared__ float cys[FJPER];
    for (int jj = tid; jj < FJPER; jj += BLOCK) {
        const float4* yv = (const float4*)(Y + (size_t)(j0 + jj) * D);
        float ny = 0.f;
#pragma unroll
        for (int q = 0; q < D / 4; ++q) {
            float4 y = yv[q];
            ny += y.x * y.x + y.y * y.y + y.z * y.z + y.w * y.w;
        }
        cys[jj] = -0.5f * ny - C16LN2PI;
    }
    __syncthreads();
    if (i >= N) return;
    float4 xv[D / 4];
    const float4* xp = (const float4*)(X + (size_t)i * D);
    float nx = 0.f;
#pragma unroll
    for (int q = 0; q < D / 4; ++q) {
        xv[q] = xp[q];
        nx += xv[q].x * xv[q].x + xv[q].y * xv[q].y + xv[q].z * xv[q].z + xv[q].w * xv[q].w;
    }
    const float cxs = -0.5f * nx;
    float acc = 0.f;
#pragma unroll 2
    for (int j = 0; j < FJPER; ++j) {
        const float4* yv = (const float4*)(Y + (size_t)(j0 + j) * D);
        float d0 = 0.f, d1 = 0.f, d2 = 0.f, d3 = 0.f;
#pragma unroll
        for (int q = 0; q < D / 4; ++q) {
            float4 y = yv[q];
            d0 = fmaf(xv[q].x, y.x, d0);
            d1 = fmaf(xv[q].y, y.y, d1);
            d2 = fmaf(xv[q].z, y.z, d2);
            d3 = fmaf(xv[q].w, y.w, d3);
        }
        acc += __expf((d0 + d1) + (d2 + d3) + cxs + cys[j]);
    }
    atomicAdd(&out[i], acc * inv_n);
}

// ---------------- launch -------------------------------------------------------
extern "C" void kernel_launch(void* const* d_in, const int* in_sizes, int n_in,
                              void* d_out, int out_size, void* d_ws, size_t ws_size,
                              hipStream_t stream) {
    (void)n_in;
    const float* X = (const float*)d_in[0];
    const float* Y = (const float*)d_in[1];
    float* out = (float*)d_out;
    const int N = in_sizes[0] / D;
    const int M = in_sizes[1] / D;

    hipMemsetAsync(d_out, 0, (size_t)out_size * sizeof(float), stream);

    const size_t xhb = (size_t)N * D * sizeof(ushort);
    const size_t yhb = (size_t)M * D * sizeof(ushort);
    const size_t cxb = (size_t)N * sizeof(float);
    const size_t cyb = (size_t)M * sizeof(float);
    const size_t need = 2 * xhb + 2 * yhb + cxb + cyb;

    const int jchunk = M / SPLITS;
    const int ntile = jchunk >> 4;
    const bool ok = (ws_size >= need) && (N % ROWS_PER_BLOCK == 0) &&
                    (M % (16 * SPLITS) == 0) && (ntile >= 4) && ((ntile & 1) == 0);

    if (!ok) {
        dim3 grid((N + BLOCK - 1) / BLOCK, FJSPLIT);
        kde_valu<<<grid, BLOCK, 0, stream>>>(X, Y, out, N, M, 1.0f / (float)N);
        return;
    }

    char* w = (char*)d_ws;
    ushort* Xhi = (ushort*)w;              w += xhb;
    ushort* Xlo = (ushort*)w;              w += xhb;
    ushort* Yhi = (ushort*)w;              w += yhb;
    ushort* Ylo = (ushort*)w;              w += yhb;
    float*  cxv = (float*)w;               w += cxb;
    float*  cyv = (float*)w;

    const float extraY = (float)((double)LOG2E *
        (-16.0 * log(2.0 * M_PI) - log((double)N)));

    cvt_kernel<<<(N + BLOCK - 1) / BLOCK, BLOCK, 0, stream>>>(X, Xhi, Xlo, cxv, N, 0.f);
    cvt_kernel<<<(M + BLOCK - 1) / BLOCK, BLOCK, 0, stream>>>(Y, Yhi, Ylo, cyv, M, extraY);

    dim3 grid(N / ROWS_PER_BLOCK, SPLITS);
    kde_mfma<<<grid, BLOCK, 0, stream>>>(Xhi, Xlo, Yhi, Ylo, cxv, cyv, out, jchunk);
}

// Round 9
// 58.123 us; speedup vs baseline: 5.5116x; 1.1842x over previous
//
#include <hip/hip_runtime.h>
#include <math.h>

// GaussianKDE: out[i] = (1/N) * sum_j exp(x_i.y_j - 0.5||x_i||^2 - 0.5||y_j||^2 - 16*ln(2pi))
// N = M = 16384, D = 32, f32 in/out.
//
// R9: f16 2-term dot. R6/R7/R8 showed wall ~= VALU_busy + MFMA_busy (~30+21us)
// invariant under 3 different schedules -> issue work must SHRINK, not reorder.
// dot ~= (xh+xl).yh with f16 split of X (21-bit) and f16-rounded Y: 2 MFMAs
// instead of 3, half the B traffic. Dropped x.yl term is a zero-mean RNE
// residual that cancels over the 16384-term j-sum (worst bound 2e-17 << 5.5e-16
// threshold). Same verified 16x16x32 fragment layout as the bf16 family.

#define D 32
#define BLOCK 256
#define WAVES 4
#define WT 4                       // 16-row i-tiles per wave
#define ROWS_PER_WAVE (WT * 16)    // 64
#define ROWS_PER_BLOCK (WAVES * ROWS_PER_WAVE)  // 256
#define SPLITS 32

#define LOG2E 1.4426950408889634f
#define SQRT_LOG2E 1.2011224087864498f

typedef __attribute__((ext_vector_type(8))) _Float16 f16x8;
typedef __attribute__((ext_vector_type(4))) float f32x4;

static __device__ __forceinline__ float fast_exp2(float x) {
    return __builtin_amdgcn_exp2f(x);   // v_exp_f32, compiler-visible (R6 fix)
}

#define MFMA16F(A, B, C) __builtin_amdgcn_mfma_f32_16x16x32_f16((A), (B), (C), 0, 0, 0)

// ---- precompute X: f16 hi/lo split of sqrt(log2e)-scaled rows + cx ----------
__global__ void cvt_x(const float* __restrict__ src, _Float16* __restrict__ hi,
                      _Float16* __restrict__ lo, float* __restrict__ cx, int rows)
{
    int r = blockIdx.x * blockDim.x + threadIdx.x;
    if (r >= rows) return;
    const float4* p = (const float4*)(src + (size_t)r * D);
    float v[D];
    float nrm = 0.f;
#pragma unroll
    for (int q = 0; q < D / 4; ++q) {
        float4 f = p[q];
        v[q * 4 + 0] = f.x; v[q * 4 + 1] = f.y; v[q * 4 + 2] = f.z; v[q * 4 + 3] = f.w;
        nrm += f.x * f.x + f.y * f.y + f.z * f.z + f.w * f.w;
    }
    cx[r] = -0.5f * LOG2E * nrm;                 // exact f32 norm
    _Float16 hb[D], lb[D];
#pragma unroll
    for (int k = 0; k < D; ++k) {
        float s = v[k] * SQRT_LOG2E;
        _Float16 h = (_Float16)s;                // RNE
        hb[k] = h;
        lb[k] = (_Float16)(s - (float)h);
    }
    f16x8* ho = (f16x8*)(hi + (size_t)r * D);
    f16x8* lo8 = (f16x8*)(lo + (size_t)r * D);
#pragma unroll
    for (int q = 0; q < D / 8; ++q) {
        f16x8 a, b;
#pragma unroll
        for (int e = 0; e < 8; ++e) { a[e] = hb[q * 8 + e]; b[e] = lb[q * 8 + e]; }
        ho[q] = a; lo8[q] = b;
    }
}

// ---- precompute Y: f16 round of scaled rows + cy (log2-domain const) --------
__global__ void cvt_y(const float* __restrict__ src, _Float16* __restrict__ yh,
                      float* __restrict__ cy, int rows, float extra)
{
    int r = blockIdx.x * blockDim.x + threadIdx.x;
    if (r >= rows) return;
    const float4* p = (const float4*)(src + (size_t)r * D);
    float v[D];
    float nrm = 0.f;
#pragma unroll
    for (int q = 0; q < D / 4; ++q) {
        float4 f = p[q];
        v[q * 4 + 0] = f.x; v[q * 4 + 1] = f.y; v[q * 4 + 2] = f.z; v[q * 4 + 3] = f.w;
        nrm += f.x * f.x + f.y * f.y + f.z * f.z + f.w * f.w;
    }
    cy[r] = -0.5f * LOG2E * nrm + extra;         // exact f32 norm + consts
    _Float16 hb[D];
#pragma unroll
    for (int k = 0; k < D; ++k)
        hb[k] = (_Float16)(v[k] * SQRT_LOG2E);
    f16x8* ho = (f16x8*)(yh + (size_t)r * D);
#pragma unroll
    for (int q = 0; q < D / 8; ++q) {
        f16x8 a;
#pragma unroll
        for (int e = 0; e < 8; ++e) a[e] = hb[q * 8 + e];
        ho[q] = a;
    }
}

// ---- main MFMA kernel --------------------------------------------------------
__global__ __launch_bounds__(BLOCK, 4) void kde_mfma(
    const _Float16* __restrict__ Xhi, const _Float16* __restrict__ Xlo,
    const _Float16* __restrict__ Yh,
    const float* __restrict__ cx, const float* __restrict__ cy,
    float* __restrict__ out, int jchunk)
{
    const int lane = threadIdx.x & 63;
    const int wave = threadIdx.x >> 6;
    const int i0 = (blockIdx.x * WAVES + wave) * ROWS_PER_WAVE;
    const int j0 = blockIdx.y * jchunk;
    const int fr = lane & 15;        // A-row / B-col / C-col within tile
    const int ks = (lane >> 4) * 8;  // K slice base

    f16x8 ahi[WT], alo[WT];
#pragma unroll
    for (int t = 0; t < WT; ++t) {
        size_t off = (size_t)(i0 + t * 16 + fr) * D + ks;
        ahi[t] = *(const f16x8*)(Xhi + off);
        alo[t] = *(const f16x8*)(Xlo + off);
    }

    float rs[WT][4];
#pragma unroll
    for (int t = 0; t < WT; ++t)
#pragma unroll
        for (int r = 0; r < 4; ++r) rs[t][r] = 0.f;

    const int ntile = jchunk >> 4;   // even, >= 4 guaranteed by launch guard
    const _Float16* bp = Yh + (size_t)(j0 + fr) * D + ks;
    const float*   cyp = cy + j0 + fr;

    f16x8 bh0 = *(const f16x8*)(bp);
    float cv0 = cyp[0];
    f16x8 bh1 = *(const f16x8*)(bp + 16 * D);
    float cv1 = cyp[16];

    f32x4 acc0[WT], acc1[WT];

    for (int jt = 0; jt < ntile - 2; jt += 2) {
        // unconditional depth-2 prefetch (always in range: jt+3 <= ntile-1)
        const f16x8 nh0 = *(const f16x8*)(bp + 32 * D);
        const float nc0 = cyp[32];
        const f16x8 nh1 = *(const f16x8*)(bp + 48 * D);
        const float nc1 = cyp[48];

        {
            const f32x4 cc0 = {cv0, cv0, cv0, cv0};   // cy in MFMA C operand
#pragma unroll
            for (int t = 0; t < WT; ++t) {
                f32x4 a = MFMA16F(ahi[t], bh0, cc0);
                acc0[t] = MFMA16F(alo[t], bh0, a);
            }
        }
        {
            const f32x4 cc1 = {cv1, cv1, cv1, cv1};
#pragma unroll
            for (int t = 0; t < WT; ++t) {
                f32x4 a = MFMA16F(ahi[t], bh1, cc1);
                acc1[t] = MFMA16F(alo[t], bh1, a);
            }
        }
#pragma unroll
        for (int t = 0; t < WT; ++t)
#pragma unroll
            for (int r = 0; r < 4; ++r)
                rs[t][r] += fast_exp2(acc0[t][r]);    // VALU overlaps acc1 MFMAs
#pragma unroll
        for (int t = 0; t < WT; ++t)
#pragma unroll
            for (int r = 0; r < 4; ++r)
                rs[t][r] += fast_exp2(acc1[t][r]);

        bh0 = nh0; cv0 = nc0; bh1 = nh1; cv1 = nc1;
        bp += 32 * D; cyp += 32;
    }

    // tail: last two tiles from registers
    {
        const f32x4 cc0 = {cv0, cv0, cv0, cv0};
        const f32x4 cc1 = {cv1, cv1, cv1, cv1};
#pragma unroll
        for (int t = 0; t < WT; ++t) {
            f32x4 a = MFMA16F(ahi[t], bh0, cc0);
            acc0[t] = MFMA16F(alo[t], bh0, a);
        }
#pragma unroll
        for (int t = 0; t < WT; ++t) {
            f32x4 a = MFMA16F(ahi[t], bh1, cc1);
            acc1[t] = MFMA16F(alo[t], bh1, a);
        }
#pragma unroll
        for (int t = 0; t < WT; ++t)
#pragma unroll
            for (int r = 0; r < 4; ++r)
                rs[t][r] += fast_exp2(acc0[t][r]);
#pragma unroll
        for (int t = 0; t < WT; ++t)
#pragma unroll
            for (int r = 0; r < 4; ++r)
                rs[t][r] += fast_exp2(acc1[t][r]);
    }

    // reduce across the 16 cols (lanes sharing lane>>4)
#pragma unroll
    for (int m = 1; m < 16; m <<= 1)
#pragma unroll
        for (int t = 0; t < WT; ++t)
#pragma unroll
            for (int r = 0; r < 4; ++r)
                rs[t][r] += __shfl_xor(rs[t][r], m, 64);

    if (fr == 0) {
        const int rowbase = i0 + (lane >> 4) * 4;
#pragma unroll
        for (int t = 0; t < WT; ++t)
#pragma unroll
            for (int r = 0; r < 4; ++r) {
                const int row = rowbase + t * 16 + r;
                atomicAdd(&out[row], rs[t][r] * fast_exp2(cx[row]));
            }
    }
}

// ---- fallback: verified R1 f32 VALU kernel ----------------------------------
#define FJSPLIT 16
#define FJPER 1024
#define C16LN2PI 29.406033062549527f

__global__ __launch_bounds__(BLOCK, 2) void kde_valu(
    const float* __restrict__ X, const float* __restrict__ Y,
    float* __restrict__ out, int N, int M, float inv_n)
{
    const int tid = threadIdx.x;
    const int i   = blockIdx.x * BLOCK + tid;
    const int j0  = blockIdx.y * FJPER;
    __shared__ float cys[FJPER];
    for (int jj = tid; jj < FJPER; jj += BLOCK) {
        const float4* yv = (const float4*)(Y + (size_t)(j0 + jj) * D);
        float ny = 0.f;
#pragma unroll
        for (int q = 0; q < D / 4; ++q) {
            float4 y = yv[q];
            ny += y.x * y.x + y.y * y.y + y.z * y.z + y.w * y.w;
        }
        cys[jj] = -0.5f * ny - C16LN2PI;
    }
    __syncthreads();
    if (i >= N) return;
    float4 xv[D / 4];
    const float4* xp = (const float4*)(X + (size_t)i * D);
    float nx = 0.f;
#pragma unroll
    for (int q = 0; q < D / 4; ++q) {
        xv[q] = xp[q];
        nx += xv[q].x * xv[q].x + xv[q].y * xv[q].y + xv[q].z * xv[q].z + xv[q].w * xv[q].w;
    }
    const float cxs = -0.5f * nx;
    float acc = 0.f;
#pragma unroll 2
    for (int j = 0; j < FJPER; ++j) {
        const float4* yv = (const float4*)(Y + (size_t)(j0 + j) * D);
        float d0 = 0.f, d1 = 0.f, d2 = 0.f, d3 = 0.f;
#pragma unroll
        for (int q = 0; q < D / 4; ++q) {
            float4 y = yv[q];
            d0 = fmaf(xv[q].x, y.x, d0);
            d1 = fmaf(xv[q].y, y.y, d1);
            d2 = fmaf(xv[q].z, y.z, d2);
            d3 = fmaf(xv[q].w, y.w, d3);
        }
        acc += __expf((d0 + d1) + (d2 + d3) + cxs + cys[j]);
    }
    atomicAdd(&out[i], acc * inv_n);
}

// ---- launch ------------------------------------------------------------------
extern "C" void kernel_launch(void* const* d_in, const int* in_sizes, int n_in,
                              void* d_out, int out_size, void* d_ws, size_t ws_size,
                              hipStream_t stream) {
    (void)n_in;
    const float* X = (const float*)d_in[0];
    const float* Y = (const float*)d_in[1];
    float* out = (float*)d_out;
    const int N = in_sizes[0] / D;
    const int M = in_sizes[1] / D;

    hipMemsetAsync(d_out, 0, (size_t)out_size * sizeof(float), stream);

    const size_t xhb = (size_t)N * D * sizeof(_Float16);
    const size_t yhb = (size_t)M * D * sizeof(_Float16);
    const size_t cxb = (size_t)N * sizeof(float);
    const size_t cyb = (size_t)M * sizeof(float);
    const size_t need = 2 * xhb + yhb + cxb + cyb;

    const int jchunk = M / SPLITS;
    const int ntile = jchunk >> 4;
    const bool ok = (ws_size >= need) && (N % ROWS_PER_BLOCK == 0) &&
                    (M % (16 * SPLITS) == 0) && (ntile >= 4) && ((ntile & 1) == 0);

    if (!ok) {
        dim3 grid((N + BLOCK - 1) / BLOCK, FJSPLIT);
        kde_valu<<<grid, BLOCK, 0, stream>>>(X, Y, out, N, M, 1.0f / (float)N);
        return;
    }

    char* w = (char*)d_ws;
    _Float16* Xhi = (_Float16*)w;          w += xhb;
    _Float16* Xlo = (_Float16*)w;          w += xhb;
    _Float16* Yhp = (_Float16*)w;          w += yhb;
    float*    cxv = (float*)w;             w += cxb;
    float*    cyv = (float*)w;

    const float extraY = (float)((double)LOG2E *
        (-16.0 * log(2.0 * M_PI) - log((double)N)));

    cvt_x<<<(N + BLOCK - 1) / BLOCK, BLOCK, 0, stream>>>(X, Xhi, Xlo, cxv, N);
    cvt_y<<<(M + BLOCK - 1) / BLOCK, BLOCK, 0, stream>>>(Y, Yhp, cyv, M, extraY);

    dim3 grid(N / ROWS_PER_BLOCK, SPLITS);
    kde_mfma<<<grid, BLOCK, 0, stream>>>(Xhi, Xlo, Yhp, cxv, cyv, out, jchunk);
}

// Round 10
// 48.021 us; speedup vs baseline: 6.6712x; 1.2104x over previous
//
#include <hip/hip_runtime.h>
#include <math.h>

// GaussianKDE: out[i] = (1/N) * sum_j exp(x_i.y_j - 0.5||x_i||^2 - 0.5||y_j||^2 - 16*ln(2pi))
// N = M = 16384, D = 32, f32 in/out.
//
// R10 = R9 base, ONE change: pure f16 1-term dot (drop Xlo + 2nd MFMA).
// log2-domain exponent err <= 0.011 worst (2^-11 RNE on x,y over 32 dims)
// -> <=0.8% worst / ~0.14% typical on exp terms -> out err ~4e-17..2e-16
// vs 5.5e-16 threshold. MFMA busy 14->7us, A fetch halves, chain 2->1.
// Ledger (R9): trans ~13.7us floor, adds ~3.4, other VALU ~8, MFMA 14,
// stalls ~9. This cuts the MFMA term; trans floor is the end game.

#define D 32
#define BLOCK 256
#define WAVES 4
#define WT 4                       // 16-row i-tiles per wave
#define ROWS_PER_WAVE (WT * 16)    // 64
#define ROWS_PER_BLOCK (WAVES * ROWS_PER_WAVE)  // 256
#define SPLITS 32

#define LOG2E 1.4426950408889634f
#define SQRT_LOG2E 1.2011224087864498f

typedef __attribute__((ext_vector_type(8))) _Float16 f16x8;
typedef __attribute__((ext_vector_type(4))) float f32x4;

static __device__ __forceinline__ float fast_exp2(float x) {
    return __builtin_amdgcn_exp2f(x);   // v_exp_f32, compiler-visible (R6 fix)
}

#define MFMA16F(A, B, C) __builtin_amdgcn_mfma_f32_16x16x32_f16((A), (B), (C), 0, 0, 0)

// ---- precompute X: f16 round of sqrt(log2e)-scaled rows + cx ----------------
__global__ void cvt_x(const float* __restrict__ src, _Float16* __restrict__ hi,
                      float* __restrict__ cx, int rows)
{
    int r = blockIdx.x * blockDim.x + threadIdx.x;
    if (r >= rows) return;
    const float4* p = (const float4*)(src + (size_t)r * D);
    float v[D];
    float nrm = 0.f;
#pragma unroll
    for (int q = 0; q < D / 4; ++q) {
        float4 f = p[q];
        v[q * 4 + 0] = f.x; v[q * 4 + 1] = f.y; v[q * 4 + 2] = f.z; v[q * 4 + 3] = f.w;
        nrm += f.x * f.x + f.y * f.y + f.z * f.z + f.w * f.w;
    }
    cx[r] = -0.5f * LOG2E * nrm;                 // exact f32 norm
    _Float16 hb[D];
#pragma unroll
    for (int k = 0; k < D; ++k)
        hb[k] = (_Float16)(v[k] * SQRT_LOG2E);   // RNE
    f16x8* ho = (f16x8*)(hi + (size_t)r * D);
#pragma unroll
    for (int q = 0; q < D / 8; ++q) {
        f16x8 a;
#pragma unroll
        for (int e = 0; e < 8; ++e) a[e] = hb[q * 8 + e];
        ho[q] = a;
    }
}

// ---- precompute Y: f16 round of scaled rows + cy (log2-domain const) --------
__global__ void cvt_y(const float* __restrict__ src, _Float16* __restrict__ yh,
                      float* __restrict__ cy, int rows, float extra)
{
    int r = blockIdx.x * blockDim.x + threadIdx.x;
    if (r >= rows) return;
    const float4* p = (const float4*)(src + (size_t)r * D);
    float v[D];
    float nrm = 0.f;
#pragma unroll
    for (int q = 0; q < D / 4; ++q) {
        float4 f = p[q];
        v[q * 4 + 0] = f.x; v[q * 4 + 1] = f.y; v[q * 4 + 2] = f.z; v[q * 4 + 3] = f.w;
        nrm += f.x * f.x + f.y * f.y + f.z * f.z + f.w * f.w;
    }
    cy[r] = -0.5f * LOG2E * nrm + extra;         // exact f32 norm + consts
    _Float16 hb[D];
#pragma unroll
    for (int k = 0; k < D; ++k)
        hb[k] = (_Float16)(v[k] * SQRT_LOG2E);
    f16x8* ho = (f16x8*)(yh + (size_t)r * D);
#pragma unroll
    for (int q = 0; q < D / 8; ++q) {
        f16x8 a;
#pragma unroll
        for (int e = 0; e < 8; ++e) a[e] = hb[q * 8 + e];
        ho[q] = a;
    }
}

// ---- main MFMA kernel --------------------------------------------------------
__global__ __launch_bounds__(BLOCK, 4) void kde_mfma(
    const _Float16* __restrict__ Xh, const _Float16* __restrict__ Yh,
    const float* __restrict__ cx, const float* __restrict__ cy,
    float* __restrict__ out, int jchunk)
{
    const int lane = threadIdx.x & 63;
    const int wave = threadIdx.x >> 6;
    const int i0 = (blockIdx.x * WAVES + wave) * ROWS_PER_WAVE;
    const int j0 = blockIdx.y * jchunk;
    const int fr = lane & 15;        // A-row / B-col / C-col within tile
    const int ks = (lane >> 4) * 8;  // K slice base

    f16x8 ax[WT];
#pragma unroll
    for (int t = 0; t < WT; ++t)
        ax[t] = *(const f16x8*)(Xh + (size_t)(i0 + t * 16 + fr) * D + ks);

    float rs[WT][4];
#pragma unroll
    for (int t = 0; t < WT; ++t)
#pragma unroll
        for (int r = 0; r < 4; ++r) rs[t][r] = 0.f;

    const int ntile = jchunk >> 4;   // even, >= 4 guaranteed by launch guard
    const _Float16* bp = Yh + (size_t)(j0 + fr) * D + ks;
    const float*   cyp = cy + j0 + fr;

    f16x8 bh0 = *(const f16x8*)(bp);
    float cv0 = cyp[0];
    f16x8 bh1 = *(const f16x8*)(bp + 16 * D);
    float cv1 = cyp[16];

    f32x4 acc0[WT], acc1[WT];

    for (int jt = 0; jt < ntile - 2; jt += 2) {
        // unconditional depth-2 prefetch (always in range: jt+3 <= ntile-1)
        const f16x8 nh0 = *(const f16x8*)(bp + 32 * D);
        const float nc0 = cyp[32];
        const f16x8 nh1 = *(const f16x8*)(bp + 48 * D);
        const float nc1 = cyp[48];

        {
            const f32x4 cc0 = {cv0, cv0, cv0, cv0};   // cy in MFMA C operand
#pragma unroll
            for (int t = 0; t < WT; ++t)
                acc0[t] = MFMA16F(ax[t], bh0, cc0);
        }
        {
            const f32x4 cc1 = {cv1, cv1, cv1, cv1};
#pragma unroll
            for (int t = 0; t < WT; ++t)
                acc1[t] = MFMA16F(ax[t], bh1, cc1);
        }
#pragma unroll
        for (int t = 0; t < WT; ++t)
#pragma unroll
            for (int r = 0; r < 4; ++r)
                rs[t][r] += fast_exp2(acc0[t][r]);    // VALU overlaps acc1 MFMAs
#pragma unroll
        for (int t = 0; t < WT; ++t)
#pragma unroll
            for (int r = 0; r < 4; ++r)
                rs[t][r] += fast_exp2(acc1[t][r]);

        bh0 = nh0; cv0 = nc0; bh1 = nh1; cv1 = nc1;
        bp += 32 * D; cyp += 32;
    }

    // tail: last two tiles from registers
    {
        const f32x4 cc0 = {cv0, cv0, cv0, cv0};
        const f32x4 cc1 = {cv1, cv1, cv1, cv1};
#pragma unroll
        for (int t = 0; t < WT; ++t)
            acc0[t] = MFMA16F(ax[t], bh0, cc0);
#pragma unroll
        for (int t = 0; t < WT; ++t)
            acc1[t] = MFMA16F(ax[t], bh1, cc1);
#pragma unroll
        for (int t = 0; t < WT; ++t)
#pragma unroll
            for (int r = 0; r < 4; ++r)
                rs[t][r] += fast_exp2(acc0[t][r]);
#pragma unroll
        for (int t = 0; t < WT; ++t)
#pragma unroll
            for (int r = 0; r < 4; ++r)
                rs[t][r] += fast_exp2(acc1[t][r]);
    }

    // reduce across the 16 cols (lanes sharing lane>>4)
#pragma unroll
    for (int m = 1; m < 16; m <<= 1)
#pragma unroll
        for (int t = 0; t < WT; ++t)
#pragma unroll
            for (int r = 0; r < 4; ++r)
                rs[t][r] += __shfl_xor(rs[t][r], m, 64);

    if (fr == 0) {
        const int rowbase = i0 + (lane >> 4) * 4;
#pragma unroll
        for (int t = 0; t < WT; ++t)
#pragma unroll
            for (int r = 0; r < 4; ++r) {
                const int row = rowbase + t * 16 + r;
                atomicAdd(&out[row], rs[t][r] * fast_exp2(cx[row]));
            }
    }
}

// ---- fallback: verified R1 f32 VALU kernel ----------------------------------
#define FJSPLIT 16
#define FJPER 1024
#define C16LN2PI 29.406033062549527f

__global__ __launch_bounds__(BLOCK, 2) void kde_valu(
    const float* __restrict__ X, const float* __restrict__ Y,
    float* __restrict__ out, int N, int M, float inv_n)
{
    const int tid = threadIdx.x;
    const int i   = blockIdx.x * BLOCK + tid;
    const int j0  = blockIdx.y * FJPER;
    __shared__ float cys[FJPER];
    for (int jj = tid; jj < FJPER; jj += BLOCK) {
        const float4* yv = (const float4*)(Y + (size_t)(j0 + jj) * D);
        float ny = 0.f;
#pragma unroll
        for (int q = 0; q < D / 4; ++q) {
            float4 y = yv[q];
            ny += y.x * y.x + y.y * y.y + y.z * y.z + y.w * y.w;
        }
        cys[jj] = -0.5f * ny - C16LN2PI;
    }
    __syncthreads();
    if (i >= N) return;
    float4 xv[D / 4];
    const float4* xp = (const float4*)(X + (size_t)i * D);
    float nx = 0.f;
#pragma unroll
    for (int q = 0; q < D / 4; ++q) {
        xv[q] = xp[q];
        nx += xv[q].x * xv[q].x + xv[q].y * xv[q].y + xv[q].z * xv[q].z + xv[q].w * xv[q].w;
    }
    const float cxs = -0.5f * nx;
    float acc = 0.f;
#pragma unroll 2
    for (int j = 0; j < FJPER; ++j) {
        const float4* yv = (const float4*)(Y + (size_t)(j0 + j) * D);
        float d0 = 0.f, d1 = 0.f, d2 = 0.f, d3 = 0.f;
#pragma unroll
        for (int q = 0; q < D / 4; ++q) {
            float4 y = yv[q];
            d0 = fmaf(xv[q].x, y.x, d0);
            d1 = fmaf(xv[q].y, y.y, d1);
            d2 = fmaf(xv[q].z, y.z, d2);
            d3 = fmaf(xv[q].w, y.w, d3);
        }
        acc += __expf((d0 + d1) + (d2 + d3) + cxs + cys[j]);
    }
    atomicAdd(&out[i], acc * inv_n);
}

// ---- launch ------------------------------------------------------------------
extern "C" void kernel_launch(void* const* d_in, const int* in_sizes, int n_in,
                              void* d_out, int out_size, void* d_ws, size_t ws_size,
                              hipStream_t stream) {
    (void)n_in;
    const float* X = (const float*)d_in[0];
    const float* Y = (const float*)d_in[1];
    float* out = (float*)d_out;
    const int N = in_sizes[0] / D;
    const int M = in_sizes[1] / D;

    hipMemsetAsync(d_out, 0, (size_t)out_size * sizeof(float), stream);

    const size_t xhb = (size_t)N * D * sizeof(_Float16);
    const size_t yhb = (size_t)M * D * sizeof(_Float16);
    const size_t cxb = (size_t)N * sizeof(float);
    const size_t cyb = (size_t)M * sizeof(float);
    const size_t need = xhb + yhb + cxb + cyb;

    const int jchunk = M / SPLITS;
    const int ntile = jchunk >> 4;
    const bool ok = (ws_size >= need) && (N % ROWS_PER_BLOCK == 0) &&
                    (M % (16 * SPLITS) == 0) && (ntile >= 4) && ((ntile & 1) == 0);

    if (!ok) {
        dim3 grid((N + BLOCK - 1) / BLOCK, FJSPLIT);
        kde_valu<<<grid, BLOCK, 0, stream>>>(X, Y, out, N, M, 1.0f / (float)N);
        return;
    }

    char* w = (char*)d_ws;
    _Float16* Xhp = (_Float16*)w;          w += xhb;
    _Float16* Yhp = (_Float16*)w;          w += yhb;
    float*    cxv = (float*)w;             w += cxb;
    float*    cyv = (float*)w;

    const float extraY = (float)((double)LOG2E *
        (-16.0 * log(2.0 * M_PI) - log((double)N)));

    cvt_x<<<(N + BLOCK - 1) / BLOCK, BLOCK, 0, stream>>>(X, Xhp, cxv, N);
    cvt_y<<<(M + BLOCK - 1) / BLOCK, BLOCK, 0, stream>>>(Y, Yhp, cyv, M, extraY);

    dim3 grid(N / ROWS_PER_BLOCK, SPLITS);
    kde_mfma<<<grid, BLOCK, 0, stream>>>(Xhp, Yhp, cxv, cyv, out, jchunk);
}